// Round 1
// baseline (4799.719 us; speedup 1.0000x reference)
//
#include <hip/hip_runtime.h>
#include <cstddef>

#define R_ 0.70710678118654752f
#define NEG_ 0.2f
#define EPS_ 1e-5f

constexpr int F_ = 64, C3_ = 192, HH_ = 128, NPIX_ = 16384, B_ = 4, LAT_ = 512, HYP_ = 33024;
// intra-row offsets inside one sample's hypernet output
constexpr int OFFI_WIN = 0, OFFI_BIN = 12288, OFFI_WMID = 12352, OFFI_BMID = 16448,
              OFFI_WOUT = 16512, OFFI_BOUT = 20608, OFFI_WSH = 20672, OFFI_BSH = 32960;
// workspace layout (float offsets)
constexpr size_t OFF_HYP = 0;                       // 4*33024 = 132096
constexpr size_t OFF_AWIN = 132096;                 // 4*192*64 = 49152
constexpr size_t OFF_AWSH = 181248;                 // 49152
constexpr size_t OFF_AWMID = 230400;                // 4*64*64 = 16384
constexpr size_t OFF_AWOUT = 246784;                // 16384
constexpr size_t OFF_ABIN = 263168;                 // 256
constexpr size_t OFF_ABSH = 263424;                 // 256
constexpr size_t OFF_STATS = 263680;                // 4*192*2 = 1536
constexpr size_t OFF_CW1 = 265216;                  // 64*9*64 = 36864
constexpr size_t OFF_CW2 = 302080;                  // 36864
constexpr size_t OFF_CWIMG = 338944;                // 64*9*3 = 1728
constexpr size_t OFF_OUT = 340672;                  // 4*64*16384 = 4194304
constexpr size_t OFF_SOB = 4534976;                 // 4*128*16384 = 8388608
constexpr size_t OFF_TMP = OFF_SOB;                 // epilogue h aliases sobel buffer
// total = 12,923,584 floats = 51.7 MB

// ---------------- hypernetwork GEMM: ws[b][j] = lat[b]·hyper_w[j] + hyper_b[j] ----
__global__ __launch_bounds__(256) void hyper_gemm_kernel(
    const float* __restrict__ lat, const float* __restrict__ hw,
    const float* __restrict__ hb, float* __restrict__ hyp) {
  __shared__ float slat[B_ * LAT_];
  const int tid = threadIdx.x;
  for (int i = tid; i < B_ * LAT_; i += 256) slat[i] = lat[i];
  __syncthreads();
  const int wave = tid >> 6, lane = tid & 63;
  const int j = blockIdx.x * 4 + wave;
  if (j >= HYP_) return;
  const float* wr = hw + (size_t)j * LAT_;
  float a0 = 0.f, a1 = 0.f, a2 = 0.f, a3 = 0.f;
  for (int i = 0; i < LAT_; i += 64) {
    float w = wr[i + lane];
    a0 = __builtin_fmaf(w, slat[0 * LAT_ + i + lane], a0);
    a1 = __builtin_fmaf(w, slat[1 * LAT_ + i + lane], a1);
    a2 = __builtin_fmaf(w, slat[2 * LAT_ + i + lane], a2);
    a3 = __builtin_fmaf(w, slat[3 * LAT_ + i + lane], a3);
  }
  #pragma unroll
  for (int off = 32; off; off >>= 1) {
    a0 += __shfl_down(a0, off, 64);
    a1 += __shfl_down(a1, off, 64);
    a2 += __shfl_down(a2, off, 64);
    a3 += __shfl_down(a3, off, 64);
  }
  if (lane == 0) {
    float b = hb[j];
    hyp[0 * HYP_ + j] = a0 + b;
    hyp[1 * HYP_ + j] = a1 + b;
    hyp[2 * HYP_ + j] = a2 + b;
    hyp[3 * HYP_ + j] = a3 + b;
  }
}

// ---------------- transpose conv weights once: [o][c][t] -> [c][t][o] ------------
__global__ __launch_bounds__(256) void prep_convw_kernel(
    const float* __restrict__ w1, const float* __restrict__ w2,
    const float* __restrict__ wi, float* __restrict__ w1t,
    float* __restrict__ w2t, float* __restrict__ wit) {
  const int idx = blockIdx.x * 256 + threadIdx.x;
  if (idx < 64 * 64 * 9) {
    int o = idx & 63, rest = idx >> 6;
    int t = rest % 9, c = rest / 9;
    w1t[idx] = w1[(o * 64 + c) * 9 + t];
    w2t[idx] = w2[(o * 64 + c) * 9 + t];
  }
  if (idx < 64 * 9 * 3) {
    int k = idx % 3, rest = idx / 3;
    int t = rest % 9, c = rest / 9;
    wit[idx] = wi[(k * 64 + c) * 9 + t];
  }
}

// ---------------- block reduction helper ----------------------------------------
__device__ __forceinline__ float blockReduceSum(float v, float* scratch) {
  const int tid = threadIdx.x;
  #pragma unroll
  for (int off = 32; off; off >>= 1) v += __shfl_down(v, off, 64);
  if ((tid & 63) == 0) scratch[tid >> 6] = v;
  __syncthreads();
  float r = scratch[0] + scratch[1] + scratch[2] + scratch[3];
  __syncthreads();
  return r;
}

// horizontal 1D filters (d = derivative, s = smoothing) for one row, one column
__device__ __forceinline__ void hline_z(const float* __restrict__ P, int rr, int col,
                                        float& hdv, float& hsv, float& cv) {
  if (rr < 0 || rr > 127) { hdv = 0.f; hsv = 0.f; cv = 0.f; return; }
  const float* rp = P + rr * HH_;
  float vm2 = (col >= 2) ? rp[col - 2] : 0.f;
  float vm1 = (col >= 1) ? rp[col - 1] : 0.f;
  float v0 = rp[col];
  float vp1 = (col <= 126) ? rp[col + 1] : 0.f;
  float vp2 = (col <= 125) ? rp[col + 2] : 0.f;
  hdv = -vm2 - R_ * vm1 + R_ * vp1 + vp2;
  hsv = R_ * vm1 + v0 + R_ * vp1;
  cv = v0;
}

// ---------------- SinSobel + InstanceNorm stats ---------------------------------
// block = (b, c) input channel; 256 threads: col = tid&127, row-half = tid>>7
__global__ __launch_bounds__(256) void sobel_stats_kernel(
    const float* __restrict__ outb, float* __restrict__ sob, float* __restrict__ stats) {
  __shared__ float scr[4];
  const int b = blockIdx.x >> 6, c = blockIdx.x & 63;
  const int tid = threadIdx.x;
  const int col = tid & 127;
  const int r0 = (tid >> 7) << 6;  // 0 or 64
  const float* P = outb + ((size_t)(b * F_ + c)) * NPIX_;
  float* gx = sob + ((size_t)(b * 2 * F_ + 2 * c)) * NPIX_;
  float* gy = gx + NPIX_;

  float sI = 0.f, qI = 0.f, sX = 0.f, qX = 0.f, sY = 0.f, qY = 0.f;
  float hd_m1, hd_0, hd_p1, hs_m2, hs_m1, hs_0, hs_p1;
  float td, tc;
  hline_z(P, r0 - 2, col, td, hs_m2, tc);
  hline_z(P, r0 - 1, col, hd_m1, hs_m1, tc);
  hline_z(P, r0, col, hd_0, hs_0, tc);
  sI += tc; qI += tc * tc;
  hline_z(P, r0 + 1, col, hd_p1, hs_p1, tc);
  sI += tc; qI += tc * tc;

  for (int i = 0; i < 64; ++i) {
    const int r = r0 + i;
    const int nr = r + 2;
    float hd_new, hs_new, cnew;
    hline_z(P, nr, col, hd_new, hs_new, cnew);
    if (nr <= r0 + 63) { sI += cnew; qI += cnew * cnew; }
    float gxv = R_ * (hd_m1 + hd_p1) + hd_0;
    float gyv = -hs_m2 - R_ * hs_m1 + R_ * hs_p1 + hs_new;
    gx[r * HH_ + col] = gxv;
    gy[r * HH_ + col] = gyv;
    sX += gxv; qX += gxv * gxv;
    sY += gyv; qY += gyv * gyv;
    hd_m1 = hd_0; hd_0 = hd_p1; hd_p1 = hd_new;
    hs_m2 = hs_m1; hs_m1 = hs_0; hs_0 = hs_p1; hs_p1 = hs_new;
  }
  __syncthreads();
  float tI = blockReduceSum(sI, scr);
  float tQI = blockReduceSum(qI, scr);
  float tX = blockReduceSum(sX, scr);
  float tQX = blockReduceSum(qX, scr);
  float tY = blockReduceSum(sY, scr);
  float tQY = blockReduceSum(qY, scr);
  if (tid == 0) {
    const float n = 1.f / 16384.f;
    float* st = stats + (size_t)b * C3_ * 2;
    float m;
    m = tI * n;  st[c * 2] = m;              st[c * 2 + 1] = rsqrtf(tQI * n - m * m + EPS_);
    int cx = 64 + 2 * c, cy = cx + 1;
    m = tX * n;  st[cx * 2] = m;             st[cx * 2 + 1] = rsqrtf(tQX * n - m * m + EPS_);
    m = tY * n;  st[cy * 2] = m;             st[cy * 2 + 1] = rsqrtf(tQY * n - m * m + EPS_);
  }
}

// ---------------- fold InstanceNorm into per-sample weights ---------------------
__global__ __launch_bounds__(256) void wadjust_kernel(
    const float* __restrict__ wsb) {
  float* wsm = const_cast<float*>(wsb);
  const int b = blockIdx.x;
  const float* hyp = wsb + OFF_HYP + (size_t)b * HYP_;
  const float* st = wsb + OFF_STATS + (size_t)b * C3_ * 2;
  float* aWin = wsm + OFF_AWIN + (size_t)b * 12288;
  float* aWsh = wsm + OFF_AWSH + (size_t)b * 12288;
  float* aWmid = wsm + OFF_AWMID + (size_t)b * 4096;
  float* aWout = wsm + OFF_AWOUT + (size_t)b * 4096;
  float* abIn = wsm + OFF_ABIN + b * 64;
  float* abSh = wsm + OFF_ABSH + b * 64;
  const int tid = threadIdx.x;
  for (int idx = tid; idx < 12288; idx += 256) {
    int cc = idx >> 6, o = idx & 63;
    float inv = st[cc * 2 + 1];
    aWin[idx] = hyp[OFFI_WIN + o * C3_ + cc] * inv;
    aWsh[idx] = hyp[OFFI_WSH + o * C3_ + cc] * inv;
  }
  for (int idx = tid; idx < 4096; idx += 256) {
    int cc = idx >> 6, o = idx & 63;
    aWmid[idx] = hyp[OFFI_WMID + o * 64 + cc];
    aWout[idx] = hyp[OFFI_WOUT + o * 64 + cc];
  }
  if (tid < 64) {
    int o = tid;
    float s1 = 0.f, s2 = 0.f;
    for (int cc = 0; cc < C3_; ++cc) {
      float m = st[cc * 2] * st[cc * 2 + 1];
      s1 = __builtin_fmaf(hyp[OFFI_WIN + o * C3_ + cc], m, s1);
      s2 = __builtin_fmaf(hyp[OFFI_WSH + o * C3_ + cc], m, s2);
    }
    abIn[o] = hyp[OFFI_BIN + o] - s1;
    abSh[o] = hyp[OFFI_BSH + o] - s2;
  }
}

// ---------------- fused per-pixel dynamic MLP (the hot kernel) ------------------
// thread = one pixel; all weights via uniform (scalar) loads; h1/h2 round-trip
// through a thread-private LDS column to allow runtime channel indexing.
__global__ __launch_bounds__(256, 1) void mlp_step_kernel(
    float* __restrict__ outb, const float* __restrict__ sob,
    const float* __restrict__ wsb, const float* __restrict__ leak) {
  __shared__ float hbuf[64 * 256];
  const int b = blockIdx.x >> 6;
  const int p = ((blockIdx.x & 63) << 8) + threadIdx.x;
  const float* aWin = wsb + OFF_AWIN + (size_t)b * 12288;
  const float* aWsh = wsb + OFF_AWSH + (size_t)b * 12288;
  const float* aWmid = wsb + OFF_AWMID + (size_t)b * 4096;
  const float* aWout = wsb + OFF_AWOUT + (size_t)b * 4096;
  const float* abIn = wsb + OFF_ABIN + b * 64;
  const float* abSh = wsb + OFF_ABSH + b * 64;
  const float* hyp = wsb + OFF_HYP + (size_t)b * HYP_;
  const float lf = fminf(fmaxf(leak[0], 0.001f), 1000.f);
  float* op = outb + (size_t)b * F_ * NPIX_ + p;
  const float* sp = sob + (size_t)b * 2 * F_ * NPIX_ + p;

  float hA[64], sA[64];
  #pragma unroll
  for (int o = 0; o < 64; ++o) { hA[o] = abIn[o]; sA[o] = abSh[o]; }
  // y channels 0..63 = out itself
  for (int c = 0; c < 64; ++c) {
    float yv = op[(size_t)c * NPIX_];
    const float* wi = aWin + c * 64;
    const float* wh = aWsh + c * 64;
    #pragma unroll
    for (int o = 0; o < 64; ++o) {
      hA[o] = __builtin_fmaf(yv, wi[o], hA[o]);
      sA[o] = __builtin_fmaf(yv, wh[o], sA[o]);
    }
  }
  // y channels 64..191 = sobel planes
  for (int c = 0; c < 128; ++c) {
    float yv = sp[(size_t)c * NPIX_];
    const float* wi = aWin + (64 + c) * 64;
    const float* wh = aWsh + (64 + c) * 64;
    #pragma unroll
    for (int o = 0; o < 64; ++o) {
      hA[o] = __builtin_fmaf(yv, wi[o], hA[o]);
      sA[o] = __builtin_fmaf(yv, wh[o], sA[o]);
    }
  }
  // lrelu(h1) -> LDS column
  #pragma unroll
  for (int o = 0; o < 64; ++o) {
    float v = hA[o];
    hbuf[o * 256 + threadIdx.x] = (v >= 0.f) ? v : NEG_ * v;
  }
  float h2[64];
  #pragma unroll
  for (int o = 0; o < 64; ++o) h2[o] = hyp[OFFI_BMID + o];
  for (int c = 0; c < 64; ++c) {
    float v = hbuf[c * 256 + threadIdx.x];
    const float* wm = aWmid + c * 64;
    #pragma unroll
    for (int o = 0; o < 64; ++o) h2[o] = __builtin_fmaf(v, wm[o], h2[o]);
  }
  #pragma unroll
  for (int o = 0; o < 64; ++o) {
    float v = h2[o];
    hbuf[o * 256 + threadIdx.x] = (v >= 0.f) ? v : NEG_ * v;
  }
  float h3[64];
  #pragma unroll
  for (int o = 0; o < 64; ++o) h3[o] = hyp[OFFI_BOUT + o];
  for (int c = 0; c < 64; ++c) {
    float v = hbuf[c * 256 + threadIdx.x];
    const float* wo = aWout + c * 64;
    #pragma unroll
    for (int o = 0; o < 64; ++o) h3[o] = __builtin_fmaf(v, wo[o], h3[o]);
  }
  // out += lf * (h3 + shortcut)
  #pragma unroll
  for (int o = 0; o < 64; ++o) {
    float cur = op[(size_t)o * NPIX_];
    op[(size_t)o * NPIX_] = cur + lf * (h3[o] + sA[o]);
  }
}

// ---------------- epilogue: 3x3 convs -------------------------------------------
__global__ __launch_bounds__(256, 1) void conv1_kernel(
    const float* __restrict__ in, const float* __restrict__ wT,
    const float* __restrict__ bias, float* __restrict__ outp) {
  const int b = blockIdx.x >> 6;
  const int p = ((blockIdx.x & 63) << 8) + threadIdx.x;
  const int row = p >> 7, col = p & 127;
  float acc[64];
  #pragma unroll
  for (int o = 0; o < 64; ++o) acc[o] = bias[o];
  const float* ip = in + (size_t)b * F_ * NPIX_;
  for (int c = 0; c < 64; ++c) {
    const float* pl = ip + (size_t)c * NPIX_;
    #pragma unroll
    for (int t = 0; t < 9; ++t) {
      const int dy = t / 3 - 1, dx = t % 3 - 1;
      const int r2 = row + dy, c2 = col + dx;
      float v = (r2 >= 0 && r2 < 128 && c2 >= 0 && c2 < 128) ? pl[r2 * HH_ + c2] : 0.f;
      const float* wp = wT + (c * 9 + t) * 64;
      #pragma unroll
      for (int o = 0; o < 64; ++o) acc[o] = __builtin_fmaf(v, wp[o], acc[o]);
    }
  }
  float* opz = outp + (size_t)b * F_ * NPIX_ + p;
  #pragma unroll
  for (int o = 0; o < 64; ++o) {
    float v = acc[o];
    opz[(size_t)o * NPIX_] = (v >= 0.f) ? v : NEG_ * v;
  }
}

__global__ __launch_bounds__(256, 1) void conv2_kernel(
    const float* __restrict__ h, const float* __restrict__ wT,
    const float* __restrict__ bias, float* __restrict__ outb) {
  const int b = blockIdx.x >> 6;
  const int p = ((blockIdx.x & 63) << 8) + threadIdx.x;
  const int row = p >> 7, col = p & 127;
  float acc[64];
  #pragma unroll
  for (int o = 0; o < 64; ++o) acc[o] = bias[o];
  const float* ip = h + (size_t)b * F_ * NPIX_;
  for (int c = 0; c < 64; ++c) {
    const float* pl = ip + (size_t)c * NPIX_;
    #pragma unroll
    for (int t = 0; t < 9; ++t) {
      const int dy = t / 3 - 1, dx = t % 3 - 1;
      const int r2 = row + dy, c2 = col + dx;
      float v = (r2 >= 0 && r2 < 128 && c2 >= 0 && c2 < 128) ? pl[r2 * HH_ + c2] : 0.f;
      const float* wp = wT + (c * 9 + t) * 64;
      #pragma unroll
      for (int o = 0; o < 64; ++o) acc[o] = __builtin_fmaf(v, wp[o], acc[o]);
    }
  }
  float* opz = outb + (size_t)b * F_ * NPIX_ + p;
  #pragma unroll
  for (int o = 0; o < 64; ++o) opz[(size_t)o * NPIX_] = opz[(size_t)o * NPIX_] + acc[o];
}

__global__ __launch_bounds__(256, 1) void convimg_kernel(
    const float* __restrict__ outb, const float* __restrict__ wT,
    const float* __restrict__ bias, float* __restrict__ img) {
  const int b = blockIdx.x >> 6;
  const int p = ((blockIdx.x & 63) << 8) + threadIdx.x;
  const int row = p >> 7, col = p & 127;
  float a0 = bias[0], a1 = bias[1], a2 = bias[2];
  const float* ip = outb + (size_t)b * F_ * NPIX_;
  for (int c = 0; c < 64; ++c) {
    const float* pl = ip + (size_t)c * NPIX_;
    #pragma unroll
    for (int t = 0; t < 9; ++t) {
      const int dy = t / 3 - 1, dx = t % 3 - 1;
      const int r2 = row + dy, c2 = col + dx;
      float v = (r2 >= 0 && r2 < 128 && c2 >= 0 && c2 < 128) ? pl[r2 * HH_ + c2] : 0.f;
      const float* wp = wT + (c * 9 + t) * 3;
      a0 = __builtin_fmaf(v, wp[0], a0);
      a1 = __builtin_fmaf(v, wp[1], a1);
      a2 = __builtin_fmaf(v, wp[2], a2);
    }
  }
  img[((size_t)b * 3 + 0) * NPIX_ + p] = fminf(fmaxf(a0, -1.f), 1.f);
  img[((size_t)b * 3 + 1) * NPIX_ + p] = fminf(fmaxf(a1, -1.f), 1.f);
  img[((size_t)b * 3 + 2) * NPIX_ + p] = fminf(fmaxf(a2, -1.f), 1.f);
}

extern "C" void kernel_launch(void* const* d_in, const int* in_sizes, int n_in,
                              void* d_out, int out_size, void* d_ws, size_t ws_size,
                              hipStream_t stream) {
  const float* lat = (const float*)d_in[0];
  const float* ca_init = (const float*)d_in[1];
  const float* leak = (const float*)d_in[2];
  const float* hyper_w = (const float*)d_in[3];
  const float* hyper_b = (const float*)d_in[4];
  const float* res_w1 = (const float*)d_in[5];
  const float* res_b1 = (const float*)d_in[6];
  const float* res_w2 = (const float*)d_in[7];
  const float* res_b2 = (const float*)d_in[8];
  const float* img_w = (const float*)d_in[9];
  const float* img_b = (const float*)d_in[10];
  float* out = (float*)d_out;
  float* ws = (float*)d_ws;

  hyper_gemm_kernel<<<(HYP_ + 3) / 4, 256, 0, stream>>>(lat, hyper_w, hyper_b, ws + OFF_HYP);
  prep_convw_kernel<<<144, 256, 0, stream>>>(res_w1, res_w2, img_w,
                                             ws + OFF_CW1, ws + OFF_CW2, ws + OFF_CWIMG);
  hipMemcpyAsync(ws + OFF_OUT, ca_init, (size_t)B_ * F_ * NPIX_ * sizeof(float),
                 hipMemcpyDeviceToDevice, stream);

  for (int s = 0; s < 16; ++s) {
    sobel_stats_kernel<<<256, 256, 0, stream>>>(ws + OFF_OUT, ws + OFF_SOB, ws + OFF_STATS);
    wadjust_kernel<<<4, 256, 0, stream>>>(ws);
    mlp_step_kernel<<<256, 256, 0, stream>>>(ws + OFF_OUT, ws + OFF_SOB, ws, leak);
  }

  conv1_kernel<<<256, 256, 0, stream>>>(ws + OFF_OUT, ws + OFF_CW1, res_b1, ws + OFF_TMP);
  conv2_kernel<<<256, 256, 0, stream>>>(ws + OFF_TMP, ws + OFF_CW2, res_b2, ws + OFF_OUT);
  convimg_kernel<<<256, 256, 0, stream>>>(ws + OFF_OUT, ws + OFF_CWIMG, img_b, out);
}

// Round 2
// 2811.138 us; speedup vs baseline: 1.7074x; 1.7074x over previous
//
#include <hip/hip_runtime.h>
#include <cstddef>

#define R_ 0.70710678118654752f
#define NEG_ 0.2f
#define EPS_ 1e-5f

constexpr int F_ = 64, C3_ = 192, HH_ = 128, NPIX_ = 16384, B_ = 4, LAT_ = 512, HYP_ = 33024;
// intra-row offsets inside one sample's hypernet output
constexpr int OFFI_WIN = 0, OFFI_BIN = 12288, OFFI_WMID = 12352, OFFI_BMID = 16448,
              OFFI_WOUT = 16512, OFFI_BOUT = 20608, OFFI_WSH = 20672, OFFI_BSH = 32960;
// workspace layout (float offsets)
constexpr size_t OFF_HYP = 0;                       // 4*33024 = 132096
constexpr size_t OFF_AWIN = 132096;                 // 4*192*64 = 49152
constexpr size_t OFF_AWSH = 181248;                 // 49152
constexpr size_t OFF_AWMID = 230400;                // 4*64*64 = 16384
constexpr size_t OFF_AWOUT = 246784;                // 16384
constexpr size_t OFF_ABIN = 263168;                 // 256
constexpr size_t OFF_ABSH = 263424;                 // 256
constexpr size_t OFF_STATS = 263680;                // 4*192*2 = 1536
constexpr size_t OFF_CW1 = 265216;                  // 64*9*64 = 36864
constexpr size_t OFF_CW2 = 302080;                  // 36864
constexpr size_t OFF_CWIMG = 338944;                // 64*9*3 = 1728
constexpr size_t OFF_OUT = 340672;                  // 4*64*16384 = 4194304
constexpr size_t OFF_SOB = 4534976;                 // 4*128*16384 = 8388608
constexpr size_t OFF_TMP = OFF_SOB;                 // epilogue h aliases sobel buffer
// raw partial stats [b][c64][quarter][6] = 6144 floats; aliases CW1 region —
// legal because prep_convw now runs AFTER the loop, before conv1.
constexpr size_t OFF_SRAW = OFF_CW1;

// ---------------- hypernetwork GEMM: ws[b][j] = lat[b]·hyper_w[j] + hyper_b[j] ----
__global__ __launch_bounds__(256) void hyper_gemm_kernel(
    const float* __restrict__ lat, const float* __restrict__ hw,
    const float* __restrict__ hb, float* __restrict__ hyp) {
  __shared__ float slat[B_ * LAT_];
  const int tid = threadIdx.x;
  for (int i = tid; i < B_ * LAT_; i += 256) slat[i] = lat[i];
  __syncthreads();
  const int wave = tid >> 6, lane = tid & 63;
  const int j = blockIdx.x * 4 + wave;
  if (j >= HYP_) return;
  const float* wr = hw + (size_t)j * LAT_;
  float a0 = 0.f, a1 = 0.f, a2 = 0.f, a3 = 0.f;
  for (int i = 0; i < LAT_; i += 64) {
    float w = wr[i + lane];
    a0 = __builtin_fmaf(w, slat[0 * LAT_ + i + lane], a0);
    a1 = __builtin_fmaf(w, slat[1 * LAT_ + i + lane], a1);
    a2 = __builtin_fmaf(w, slat[2 * LAT_ + i + lane], a2);
    a3 = __builtin_fmaf(w, slat[3 * LAT_ + i + lane], a3);
  }
  #pragma unroll
  for (int off = 32; off; off >>= 1) {
    a0 += __shfl_down(a0, off, 64);
    a1 += __shfl_down(a1, off, 64);
    a2 += __shfl_down(a2, off, 64);
    a3 += __shfl_down(a3, off, 64);
  }
  if (lane == 0) {
    float b = hb[j];
    hyp[0 * HYP_ + j] = a0 + b;
    hyp[1 * HYP_ + j] = a1 + b;
    hyp[2 * HYP_ + j] = a2 + b;
    hyp[3 * HYP_ + j] = a3 + b;
  }
}

// ---------------- transpose conv weights (runs AFTER the loop): [o][c][t] -> [c][t][o]
__global__ __launch_bounds__(256) void prep_convw_kernel(
    const float* __restrict__ w1, const float* __restrict__ w2,
    const float* __restrict__ wi, float* __restrict__ w1t,
    float* __restrict__ w2t, float* __restrict__ wit) {
  const int idx = blockIdx.x * 256 + threadIdx.x;
  if (idx < 64 * 64 * 9) {
    int o = idx & 63, rest = idx >> 6;
    int t = rest % 9, c = rest / 9;
    w1t[idx] = w1[(o * 64 + c) * 9 + t];
    w2t[idx] = w2[(o * 64 + c) * 9 + t];
  }
  if (idx < 64 * 9 * 3) {
    int k = idx % 3, rest = idx / 3;
    int t = rest % 9, c = rest / 9;
    wit[idx] = wi[(k * 64 + c) * 9 + t];
  }
}

// ---------------- block reduction helper ----------------------------------------
__device__ __forceinline__ float blockReduceSum(float v, float* scratch) {
  const int tid = threadIdx.x;
  #pragma unroll
  for (int off = 32; off; off >>= 1) v += __shfl_down(v, off, 64);
  if ((tid & 63) == 0) scratch[tid >> 6] = v;
  __syncthreads();
  float r = scratch[0] + scratch[1] + scratch[2] + scratch[3];
  __syncthreads();
  return r;
}

// horizontal 1D filters (d = derivative, s = smoothing) for one row, one column
__device__ __forceinline__ void hline_z(const float* __restrict__ P, int rr, int col,
                                        float& hdv, float& hsv, float& cv) {
  if (rr < 0 || rr > 127) { hdv = 0.f; hsv = 0.f; cv = 0.f; return; }
  const float* rp = P + rr * HH_;
  float vm2 = (col >= 2) ? rp[col - 2] : 0.f;
  float vm1 = (col >= 1) ? rp[col - 1] : 0.f;
  float v0 = rp[col];
  float vp1 = (col <= 126) ? rp[col + 1] : 0.f;
  float vp2 = (col <= 125) ? rp[col + 2] : 0.f;
  hdv = -vm2 - R_ * vm1 + R_ * vp1 + vp2;
  hsv = R_ * vm1 + v0 + R_ * vp1;
  cv = v0;
}

// ---------------- SinSobel + raw InstanceNorm partial sums ----------------------
// block = (b, c, quarter); 256 threads: col = tid&127, row-sub = tid>>7 (16 rows each)
__global__ __launch_bounds__(256) void sobel_stats_kernel(
    const float* __restrict__ outb, float* __restrict__ sob, float* __restrict__ sraw) {
  __shared__ float scr[4];
  const int bi = blockIdx.x;
  const int q = bi & 3, c = (bi >> 2) & 63, b = bi >> 8;
  const int tid = threadIdx.x;
  const int col = tid & 127;
  const int r0 = q * 32 + (tid >> 7) * 16;
  const float* P = outb + ((size_t)(b * F_ + c)) * NPIX_;
  float* gx = sob + ((size_t)(b * 2 * F_ + 2 * c)) * NPIX_;
  float* gy = gx + NPIX_;

  float sI = 0.f, qI = 0.f, sX = 0.f, qX = 0.f, sY = 0.f, qY = 0.f;
  float hd_m1, hd_0, hd_p1, hs_m2, hs_m1, hs_0, hs_p1;
  float td, tc;
  hline_z(P, r0 - 2, col, td, hs_m2, tc);
  hline_z(P, r0 - 1, col, hd_m1, hs_m1, tc);
  hline_z(P, r0, col, hd_0, hs_0, tc);
  sI += tc; qI += tc * tc;
  hline_z(P, r0 + 1, col, hd_p1, hs_p1, tc);
  sI += tc; qI += tc * tc;

  for (int i = 0; i < 16; ++i) {
    const int r = r0 + i;
    const int nr = r + 2;
    float hd_new, hs_new, cnew;
    hline_z(P, nr, col, hd_new, hs_new, cnew);
    if (nr <= r0 + 15) { sI += cnew; qI += cnew * cnew; }
    float gxv = R_ * (hd_m1 + hd_p1) + hd_0;
    float gyv = -hs_m2 - R_ * hs_m1 + R_ * hs_p1 + hs_new;
    gx[r * HH_ + col] = gxv;
    gy[r * HH_ + col] = gyv;
    sX += gxv; qX += gxv * gxv;
    sY += gyv; qY += gyv * gyv;
    hd_m1 = hd_0; hd_0 = hd_p1; hd_p1 = hd_new;
    hs_m2 = hs_m1; hs_m1 = hs_0; hs_0 = hs_p1; hs_p1 = hs_new;
  }
  __syncthreads();
  float tI = blockReduceSum(sI, scr);
  float tQI = blockReduceSum(qI, scr);
  float tX = blockReduceSum(sX, scr);
  float tQX = blockReduceSum(qX, scr);
  float tY = blockReduceSum(sY, scr);
  float tQY = blockReduceSum(qY, scr);
  if (tid == 0) {
    float* r = sraw + (size_t)bi * 6;
    r[0] = tI; r[1] = tQI; r[2] = tX; r[3] = tQX; r[4] = tY; r[5] = tQY;
  }
}

// ---------------- finalize stats + fold InstanceNorm into per-sample weights ----
__global__ __launch_bounds__(256) void wadjust_kernel(float* wsm) {
  const int b = blockIdx.x;
  const float* hyp = wsm + OFF_HYP + (size_t)b * HYP_;
  float* st = wsm + OFF_STATS + (size_t)b * C3_ * 2;
  const float* sraw = wsm + OFF_SRAW;
  float* aWin = wsm + OFF_AWIN + (size_t)b * 12288;
  float* aWsh = wsm + OFF_AWSH + (size_t)b * 12288;
  float* aWmid = wsm + OFF_AWMID + (size_t)b * 4096;
  float* aWout = wsm + OFF_AWOUT + (size_t)b * 4096;
  float* abIn = wsm + OFF_ABIN + b * 64;
  float* abSh = wsm + OFF_ABSH + b * 64;
  const int tid = threadIdx.x;

  if (tid < 64) {
    const int c = tid;
    const float* r = sraw + ((size_t)(b * 64 + c) * 4) * 6;
    float sI = 0.f, qI = 0.f, sX = 0.f, qX = 0.f, sY = 0.f, qY = 0.f;
    #pragma unroll
    for (int q = 0; q < 4; ++q) {
      sI += r[q * 6 + 0]; qI += r[q * 6 + 1];
      sX += r[q * 6 + 2]; qX += r[q * 6 + 3];
      sY += r[q * 6 + 4]; qY += r[q * 6 + 5];
    }
    const float n = 1.f / 16384.f;
    float m;
    m = sI * n; st[c * 2] = m;            st[c * 2 + 1] = rsqrtf(qI * n - m * m + EPS_);
    const int cx = 64 + 2 * c, cy = cx + 1;
    m = sX * n; st[cx * 2] = m;           st[cx * 2 + 1] = rsqrtf(qX * n - m * m + EPS_);
    m = sY * n; st[cy * 2] = m;           st[cy * 2 + 1] = rsqrtf(qY * n - m * m + EPS_);
  }
  __syncthreads();

  for (int idx = tid; idx < 12288; idx += 256) {
    int cc = idx >> 6, o = idx & 63;
    float inv = st[cc * 2 + 1];
    aWin[idx] = hyp[OFFI_WIN + o * C3_ + cc] * inv;
    aWsh[idx] = hyp[OFFI_WSH + o * C3_ + cc] * inv;
  }
  for (int idx = tid; idx < 4096; idx += 256) {
    int cc = idx >> 6, o = idx & 63;
    aWmid[idx] = hyp[OFFI_WMID + o * 64 + cc];
    aWout[idx] = hyp[OFFI_WOUT + o * 64 + cc];
  }
  if (tid < 64) {
    int o = tid;
    float s1 = 0.f, s2 = 0.f;
    for (int cc = 0; cc < C3_; ++cc) {
      float m = st[cc * 2] * st[cc * 2 + 1];
      s1 = __builtin_fmaf(hyp[OFFI_WIN + o * C3_ + cc], m, s1);
      s2 = __builtin_fmaf(hyp[OFFI_WSH + o * C3_ + cc], m, s2);
    }
    abIn[o] = hyp[OFFI_BIN + o] - s1;
    abSh[o] = hyp[OFFI_BSH + o] - s2;
  }
}

// ---------------- fused per-pixel dynamic MLP (the hot kernel) ------------------
// block = 128 pixels x 2 channel-halves (hf). Each thread owns 32 output channels
// for every stage; h1/h2 cross the halves via a 32 KB LDS buffer.
__global__ __launch_bounds__(256, 2) void mlp_step_kernel(
    float* __restrict__ outb, const float* __restrict__ sob,
    const float* __restrict__ wsb, const float* __restrict__ leak) {
  __shared__ float hbuf[64 * 128];
  const int bi = blockIdx.x;
  const int b = bi >> 7, pxb = bi & 127;
  const int tid = threadIdx.x;
  const int px = tid & 127;
  const int hf = __builtin_amdgcn_readfirstlane(tid >> 7);  // wave-uniform -> scalar loads
  const int p = pxb * 128 + px;
  const float* aWin = wsb + OFF_AWIN + (size_t)b * 12288 + hf * 32;
  const float* aWsh = wsb + OFF_AWSH + (size_t)b * 12288 + hf * 32;
  const float* aWmid = wsb + OFF_AWMID + (size_t)b * 4096 + hf * 32;
  const float* aWout = wsb + OFF_AWOUT + (size_t)b * 4096 + hf * 32;
  const float* abIn = wsb + OFF_ABIN + b * 64 + hf * 32;
  const float* abSh = wsb + OFF_ABSH + b * 64 + hf * 32;
  const float* hyp = wsb + OFF_HYP + (size_t)b * HYP_;
  const float lf = fminf(fmaxf(leak[0], 0.001f), 1000.f);
  float* op = outb + (size_t)b * F_ * NPIX_ + p;
  const float* sp = sob + (size_t)b * 2 * F_ * NPIX_ + p;

  float hA[32], sA[32];
  #pragma unroll
  for (int o = 0; o < 32; ++o) { hA[o] = abIn[o]; sA[o] = abSh[o]; }
  for (int c = 0; c < 64; ++c) {
    float yv = op[(size_t)c * NPIX_];
    const float* wi = aWin + c * 64;
    const float* wh = aWsh + c * 64;
    #pragma unroll
    for (int o = 0; o < 32; ++o) {
      hA[o] = __builtin_fmaf(yv, wi[o], hA[o]);
      sA[o] = __builtin_fmaf(yv, wh[o], sA[o]);
    }
  }
  for (int c = 0; c < 128; ++c) {
    float yv = sp[(size_t)c * NPIX_];
    const float* wi = aWin + (64 + c) * 64;
    const float* wh = aWsh + (64 + c) * 64;
    #pragma unroll
    for (int o = 0; o < 32; ++o) {
      hA[o] = __builtin_fmaf(yv, wi[o], hA[o]);
      sA[o] = __builtin_fmaf(yv, wh[o], sA[o]);
    }
  }
  // lrelu(h1) -> LDS
  #pragma unroll
  for (int o = 0; o < 32; ++o) {
    float v = hA[o];
    hbuf[(hf * 32 + o) * 128 + px] = (v >= 0.f) ? v : NEG_ * v;
  }
  __syncthreads();
  float h2[32];
  #pragma unroll
  for (int o = 0; o < 32; ++o) h2[o] = hyp[OFFI_BMID + hf * 32 + o];
  for (int c = 0; c < 64; ++c) {
    float v = hbuf[c * 128 + px];
    const float* wm = aWmid + c * 64;
    #pragma unroll
    for (int o = 0; o < 32; ++o) h2[o] = __builtin_fmaf(v, wm[o], h2[o]);
  }
  __syncthreads();
  #pragma unroll
  for (int o = 0; o < 32; ++o) {
    float v = h2[o];
    hbuf[(hf * 32 + o) * 128 + px] = (v >= 0.f) ? v : NEG_ * v;
  }
  __syncthreads();
  float h3[32];
  #pragma unroll
  for (int o = 0; o < 32; ++o) h3[o] = hyp[OFFI_BOUT + hf * 32 + o];
  for (int c = 0; c < 64; ++c) {
    float v = hbuf[c * 128 + px];
    const float* wo = aWout + c * 64;
    #pragma unroll
    for (int o = 0; o < 32; ++o) h3[o] = __builtin_fmaf(v, wo[o], h3[o]);
  }
  // out += lf * (h3 + shortcut)
  #pragma unroll
  for (int o = 0; o < 32; ++o) {
    const int co = hf * 32 + o;
    float cur = op[(size_t)co * NPIX_];
    op[(size_t)co * NPIX_] = cur + lf * (h3[o] + sA[o]);
  }
}

// ---------------- epilogue: 3x3 convs -------------------------------------------
// block = (b, pxb, og): 256 pixels x 16 output channels; og uniform -> scalar weights
__global__ __launch_bounds__(256, 4) void conv1_kernel(
    const float* __restrict__ in, const float* __restrict__ wT,
    const float* __restrict__ bias, float* __restrict__ outp) {
  const int bi = blockIdx.x;
  const int og = bi & 3, pxb = (bi >> 2) & 63, b = bi >> 8;
  const int p = pxb * 256 + threadIdx.x;
  const int row = p >> 7, col = p & 127;
  float acc[16];
  #pragma unroll
  for (int o = 0; o < 16; ++o) acc[o] = bias[og * 16 + o];
  const float* ip = in + (size_t)b * F_ * NPIX_;
  for (int c = 0; c < 64; ++c) {
    const float* pl = ip + (size_t)c * NPIX_;
    #pragma unroll
    for (int t = 0; t < 9; ++t) {
      const int dy = t / 3 - 1, dx = t % 3 - 1;
      const int r2 = row + dy, c2 = col + dx;
      float v = (r2 >= 0 && r2 < 128 && c2 >= 0 && c2 < 128) ? pl[r2 * HH_ + c2] : 0.f;
      const float* wp = wT + (c * 9 + t) * 64 + og * 16;
      #pragma unroll
      for (int o = 0; o < 16; ++o) acc[o] = __builtin_fmaf(v, wp[o], acc[o]);
    }
  }
  float* opz = outp + (size_t)(b * F_ + og * 16) * NPIX_ + p;
  #pragma unroll
  for (int o = 0; o < 16; ++o) {
    float v = acc[o];
    opz[(size_t)o * NPIX_] = (v >= 0.f) ? v : NEG_ * v;
  }
}

__global__ __launch_bounds__(256, 4) void conv2_kernel(
    const float* __restrict__ h, const float* __restrict__ wT,
    const float* __restrict__ bias, float* __restrict__ outb) {
  const int bi = blockIdx.x;
  const int og = bi & 3, pxb = (bi >> 2) & 63, b = bi >> 8;
  const int p = pxb * 256 + threadIdx.x;
  const int row = p >> 7, col = p & 127;
  float acc[16];
  #pragma unroll
  for (int o = 0; o < 16; ++o) acc[o] = bias[og * 16 + o];
  const float* ip = h + (size_t)b * F_ * NPIX_;
  for (int c = 0; c < 64; ++c) {
    const float* pl = ip + (size_t)c * NPIX_;
    #pragma unroll
    for (int t = 0; t < 9; ++t) {
      const int dy = t / 3 - 1, dx = t % 3 - 1;
      const int r2 = row + dy, c2 = col + dx;
      float v = (r2 >= 0 && r2 < 128 && c2 >= 0 && c2 < 128) ? pl[r2 * HH_ + c2] : 0.f;
      const float* wp = wT + (c * 9 + t) * 64 + og * 16;
      #pragma unroll
      for (int o = 0; o < 16; ++o) acc[o] = __builtin_fmaf(v, wp[o], acc[o]);
    }
  }
  float* opz = outb + (size_t)(b * F_ + og * 16) * NPIX_ + p;
  #pragma unroll
  for (int o = 0; o < 16; ++o) opz[(size_t)o * NPIX_] = opz[(size_t)o * NPIX_] + acc[o];
}

// block = 128 pixels x 2 input-channel halves; LDS combine; 3 outputs
__global__ __launch_bounds__(256, 4) void convimg_kernel(
    const float* __restrict__ outb, const float* __restrict__ wT,
    const float* __restrict__ bias, float* __restrict__ img) {
  __shared__ float part[2 * 128 * 3];
  const int bi = blockIdx.x;
  const int b = bi >> 7, pxb = bi & 127;
  const int tid = threadIdx.x;
  const int px = tid & 127;
  const int hf = __builtin_amdgcn_readfirstlane(tid >> 7);
  const int p = pxb * 128 + px;
  const int row = p >> 7, col = p & 127;
  float a0 = 0.f, a1 = 0.f, a2 = 0.f;
  const float* ip = outb + (size_t)b * F_ * NPIX_;
  for (int cc = 0; cc < 32; ++cc) {
    const int c = hf * 32 + cc;
    const float* pl = ip + (size_t)c * NPIX_;
    #pragma unroll
    for (int t = 0; t < 9; ++t) {
      const int dy = t / 3 - 1, dx = t % 3 - 1;
      const int r2 = row + dy, c2 = col + dx;
      float v = (r2 >= 0 && r2 < 128 && c2 >= 0 && c2 < 128) ? pl[r2 * HH_ + c2] : 0.f;
      const float* wp = wT + (c * 9 + t) * 3;
      a0 = __builtin_fmaf(v, wp[0], a0);
      a1 = __builtin_fmaf(v, wp[1], a1);
      a2 = __builtin_fmaf(v, wp[2], a2);
    }
  }
  part[(hf * 128 + px) * 3 + 0] = a0;
  part[(hf * 128 + px) * 3 + 1] = a1;
  part[(hf * 128 + px) * 3 + 2] = a2;
  __syncthreads();
  if (hf == 0) {
    float r0 = a0 + part[(128 + px) * 3 + 0] + bias[0];
    float r1 = a1 + part[(128 + px) * 3 + 1] + bias[1];
    float r2 = a2 + part[(128 + px) * 3 + 2] + bias[2];
    img[((size_t)b * 3 + 0) * NPIX_ + p] = fminf(fmaxf(r0, -1.f), 1.f);
    img[((size_t)b * 3 + 1) * NPIX_ + p] = fminf(fmaxf(r1, -1.f), 1.f);
    img[((size_t)b * 3 + 2) * NPIX_ + p] = fminf(fmaxf(r2, -1.f), 1.f);
  }
}

extern "C" void kernel_launch(void* const* d_in, const int* in_sizes, int n_in,
                              void* d_out, int out_size, void* d_ws, size_t ws_size,
                              hipStream_t stream) {
  const float* lat = (const float*)d_in[0];
  const float* ca_init = (const float*)d_in[1];
  const float* leak = (const float*)d_in[2];
  const float* hyper_w = (const float*)d_in[3];
  const float* hyper_b = (const float*)d_in[4];
  const float* res_w1 = (const float*)d_in[5];
  const float* res_b1 = (const float*)d_in[6];
  const float* res_w2 = (const float*)d_in[7];
  const float* res_b2 = (const float*)d_in[8];
  const float* img_w = (const float*)d_in[9];
  const float* img_b = (const float*)d_in[10];
  float* out = (float*)d_out;
  float* ws = (float*)d_ws;

  hyper_gemm_kernel<<<(HYP_ + 3) / 4, 256, 0, stream>>>(lat, hyper_w, hyper_b, ws + OFF_HYP);
  hipMemcpyAsync(ws + OFF_OUT, ca_init, (size_t)B_ * F_ * NPIX_ * sizeof(float),
                 hipMemcpyDeviceToDevice, stream);

  for (int s = 0; s < 16; ++s) {
    sobel_stats_kernel<<<1024, 256, 0, stream>>>(ws + OFF_OUT, ws + OFF_SOB, ws + OFF_SRAW);
    wadjust_kernel<<<4, 256, 0, stream>>>(ws);
    mlp_step_kernel<<<512, 256, 0, stream>>>(ws + OFF_OUT, ws + OFF_SOB, ws, leak);
  }

  // conv-weight transpose AFTER the loop (its region aliases sraw)
  prep_convw_kernel<<<144, 256, 0, stream>>>(res_w1, res_w2, img_w,
                                             ws + OFF_CW1, ws + OFF_CW2, ws + OFF_CWIMG);
  conv1_kernel<<<1024, 256, 0, stream>>>(ws + OFF_OUT, ws + OFF_CW1, res_b1, ws + OFF_TMP);
  conv2_kernel<<<1024, 256, 0, stream>>>(ws + OFF_TMP, ws + OFF_CW2, res_b2, ws + OFF_OUT);
  convimg_kernel<<<512, 256, 0, stream>>>(ws + OFF_OUT, ws + OFF_CWIMG, img_b, out);
}

// Round 4
// 1540.764 us; speedup vs baseline: 3.1152x; 1.8245x over previous
//
#include <hip/hip_runtime.h>
#include <cstddef>

#define R_ 0.70710678118654752f
#define NEG_ 0.2f
#define EPS_ 1e-5f

constexpr int F_ = 64, C3_ = 192, HH_ = 128, NPIX_ = 16384, B_ = 4, LAT_ = 512, HYP_ = 33024;
// intra-row offsets inside one sample's hypernet output
constexpr int OFFI_WIN = 0, OFFI_BIN = 12288, OFFI_WMID = 12352, OFFI_BMID = 16448,
              OFFI_WOUT = 16512, OFFI_BOUT = 20608, OFFI_WSH = 20672, OFFI_BSH = 32960;
// workspace layout (float offsets)
constexpr size_t OFF_HYP = 0;         // 132096
constexpr size_t OFF_ABIN = 132096;   // 256
constexpr size_t OFF_ABSH = 132352;   // 256 (132608..134143 spare)
constexpr size_t OFF_SRAW = 134144;   // 6144
constexpr size_t OFF_WFIN = 140288;   // 4*24576 ushort = 49152 floats (hi/lo frag pairs)
constexpr size_t OFF_WFSH = 189440;   // 49152
constexpr size_t OFF_WFMID = 238592;  // 4*8192 ushort = 16384 floats
constexpr size_t OFF_WFOUT = 254976;  // 16384
constexpr size_t OFF_CW1 = 271360;    // 36864
constexpr size_t OFF_CW2 = 308224;    // 36864
constexpr size_t OFF_CWIMG = 345088;  // 1728
constexpr size_t OFF_OUT = 346816;    // 4194304
constexpr size_t OFF_SOB = 4541120;   // 4*128*16384 packed-uint = 8388608 "floats"
constexpr size_t OFF_TMP = OFF_SOB;   // epilogue h (fp32, 4194304) aliases sob
// total = 12,929,728 floats = 51.7 MB (== round-1 footprint, known to fit)

typedef short bf16x8 __attribute__((ext_vector_type(8)));
typedef float f32x4 __attribute__((ext_vector_type(4)));

// fp32 -> bf16 (RNE)
static __device__ __forceinline__ unsigned short f2b(float v) {
  unsigned u = __builtin_bit_cast(unsigned, v);
  u += 0x7fffu + ((u >> 16) & 1u);
  return (unsigned short)(u >> 16);
}
static __device__ __forceinline__ float b2f(unsigned short h) {
  return __builtin_bit_cast(float, ((unsigned)h) << 16);
}
static __device__ __forceinline__ void split2(float v, unsigned short& hi, unsigned short& lo) {
  hi = f2b(v);
  lo = f2b(v - b2f(hi));
}

// triple-MFMA split-bf16 product: acc += Ahi*Whi + Ahi*Wlo + Alo*Whi
#define MM3(acc, ahi, alo, whi, wlo)                                        \
  acc = __builtin_amdgcn_mfma_f32_16x16x32_bf16(ahi, whi, acc, 0, 0, 0);    \
  acc = __builtin_amdgcn_mfma_f32_16x16x32_bf16(ahi, wlo, acc, 0, 0, 0);    \
  acc = __builtin_amdgcn_mfma_f32_16x16x32_bf16(alo, whi, acc, 0, 0, 0);

// ---------------- hypernetwork GEMM ----------------------------------------------
__global__ __launch_bounds__(256) void hyper_gemm_kernel(
    const float* __restrict__ lat, const float* __restrict__ hw,
    const float* __restrict__ hb, float* __restrict__ hyp) {
  __shared__ float slat[B_ * LAT_];
  const int tid = threadIdx.x;
  for (int i = tid; i < B_ * LAT_; i += 256) slat[i] = lat[i];
  __syncthreads();
  const int wave = tid >> 6, lane = tid & 63;
  const int j = blockIdx.x * 4 + wave;
  if (j >= HYP_) return;
  const float* wr = hw + (size_t)j * LAT_;
  float a0 = 0.f, a1 = 0.f, a2 = 0.f, a3 = 0.f;
  for (int i = 0; i < LAT_; i += 64) {
    float w = wr[i + lane];
    a0 = __builtin_fmaf(w, slat[0 * LAT_ + i + lane], a0);
    a1 = __builtin_fmaf(w, slat[1 * LAT_ + i + lane], a1);
    a2 = __builtin_fmaf(w, slat[2 * LAT_ + i + lane], a2);
    a3 = __builtin_fmaf(w, slat[3 * LAT_ + i + lane], a3);
  }
  #pragma unroll
  for (int off = 32; off; off >>= 1) {
    a0 += __shfl_down(a0, off, 64);
    a1 += __shfl_down(a1, off, 64);
    a2 += __shfl_down(a2, off, 64);
    a3 += __shfl_down(a3, off, 64);
  }
  if (lane == 0) {
    float b = hb[j];
    hyp[0 * HYP_ + j] = a0 + b;
    hyp[1 * HYP_ + j] = a1 + b;
    hyp[2 * HYP_ + j] = a2 + b;
    hyp[3 * HYP_ + j] = a3 + b;
  }
}

// ---------------- transpose conv weights: [o][c][t] -> [c][t][o] ------------------
__global__ __launch_bounds__(256) void prep_convw_kernel(
    const float* __restrict__ w1, const float* __restrict__ w2,
    const float* __restrict__ wi, float* __restrict__ w1t,
    float* __restrict__ w2t, float* __restrict__ wit) {
  const int idx = blockIdx.x * 256 + threadIdx.x;
  if (idx < 64 * 64 * 9) {
    int o = idx & 63, rest = idx >> 6;
    int t = rest % 9, c = rest / 9;
    w1t[idx] = w1[(o * 64 + c) * 9 + t];
    w2t[idx] = w2[(o * 64 + c) * 9 + t];
  }
  if (idx < 64 * 9 * 3) {
    int k = idx % 3, rest = idx / 3;
    int t = rest % 9, c = rest / 9;
    wit[idx] = wi[(k * 64 + c) * 9 + t];
  }
}

// ---------------- block reduction helper ------------------------------------------
__device__ __forceinline__ float blockReduceSum(float v, float* scratch) {
  const int tid = threadIdx.x;
  #pragma unroll
  for (int off = 32; off; off >>= 1) v += __shfl_down(v, off, 64);
  if ((tid & 63) == 0) scratch[tid >> 6] = v;
  __syncthreads();
  float r = scratch[0] + scratch[1] + scratch[2] + scratch[3];
  __syncthreads();
  return r;
}

__device__ __forceinline__ void hline_z(const float* __restrict__ P, int rr, int col,
                                        float& hdv, float& hsv, float& cv) {
  if (rr < 0 || rr > 127) { hdv = 0.f; hsv = 0.f; cv = 0.f; return; }
  const float* rp = P + rr * HH_;
  float vm2 = (col >= 2) ? rp[col - 2] : 0.f;
  float vm1 = (col >= 1) ? rp[col - 1] : 0.f;
  float v0 = rp[col];
  float vp1 = (col <= 126) ? rp[col + 1] : 0.f;
  float vp2 = (col <= 125) ? rp[col + 2] : 0.f;
  hdv = -vm2 - R_ * vm1 + R_ * vp1 + vp2;
  hsv = R_ * vm1 + v0 + R_ * vp1;
  cv = v0;
}

// ---------------- SinSobel -> packed split-bf16 gx/gy + raw IN partials -----------
// sob: [b][128][16384] uint32, (hi<<16)|lo split-bf16. ch 2c = gx(c), 2c+1 = gy(c)
__global__ __launch_bounds__(256) void sobel_stats_kernel(
    const float* __restrict__ outb, unsigned int* __restrict__ sob,
    float* __restrict__ sraw) {
  __shared__ float scr[4];
  const int bi = blockIdx.x;
  const int q = bi & 3, c = (bi >> 2) & 63, b = bi >> 8;
  const int tid = threadIdx.x;
  const int col = tid & 127;
  const int r0 = q * 32 + (tid >> 7) * 16;
  const float* P = outb + ((size_t)(b * F_ + c)) * NPIX_;
  unsigned int* ygx = sob + ((size_t)(b * 128 + 2 * c)) * NPIX_;
  unsigned int* ygy = ygx + NPIX_;

  float sI = 0.f, qI = 0.f, sX = 0.f, qX = 0.f, sY = 0.f, qY = 0.f;
  float hd_m1, hd_0, hd_p1, hs_m2, hs_m1, hs_0, hs_p1;
  float td, tc;
  hline_z(P, r0 - 2, col, td, hs_m2, tc);
  hline_z(P, r0 - 1, col, hd_m1, hs_m1, tc);
  hline_z(P, r0, col, hd_0, hs_0, tc);
  sI += tc; qI += tc * tc;
  hline_z(P, r0 + 1, col, hd_p1, hs_p1, tc);
  sI += tc; qI += tc * tc;

  for (int i = 0; i < 16; ++i) {
    const int r = r0 + i;
    const int nr = r + 2;
    float hd_new, hs_new, cnew;
    hline_z(P, nr, col, hd_new, hs_new, cnew);
    if (nr <= r0 + 15) { sI += cnew; qI += cnew * cnew; }
    float gxv = R_ * (hd_m1 + hd_p1) + hd_0;
    float gyv = -hs_m2 - R_ * hs_m1 + R_ * hs_p1 + hs_new;
    const int o = r * HH_ + col;
    unsigned short h, l;
    split2(gxv, h, l);
    ygx[o] = ((unsigned)h << 16) | l;
    split2(gyv, h, l);
    ygy[o] = ((unsigned)h << 16) | l;
    sX += gxv; qX += gxv * gxv;
    sY += gyv; qY += gyv * gyv;
    hd_m1 = hd_0; hd_0 = hd_p1; hd_p1 = hd_new;
    hs_m2 = hs_m1; hs_m1 = hs_0; hs_0 = hs_p1; hs_p1 = hs_new;
  }
  __syncthreads();
  float tI = blockReduceSum(sI, scr);
  float tQI = blockReduceSum(qI, scr);
  float tX = blockReduceSum(sX, scr);
  float tQX = blockReduceSum(qX, scr);
  float tY = blockReduceSum(sY, scr);
  float tQY = blockReduceSum(qY, scr);
  if (tid == 0) {
    float* r = sraw + (size_t)bi * 6;
    r[0] = tI; r[1] = tQI; r[2] = tX; r[3] = tQX; r[4] = tY; r[5] = tQY;
  }
}

// ---------------- finalize stats + emit split-bf16 frag weights -------------------
// grid = 32: (b, slice). frag pair layout: wf[fb*16 + j] = hi, wf[fb*16+8+j] = lo,
// fb = (ks*4+g)*64 + ch, k = ks*32 + g*8 + j  (same k-map as the A-frag reads)
__global__ __launch_bounds__(256) void wadjust_kernel(float* wsm) {
  __shared__ float stl[C3_ * 2];
  const int b = blockIdx.x >> 3, sl = blockIdx.x & 7;
  const int tid = threadIdx.x;
  const float* sraw = wsm + OFF_SRAW;
  if (tid < 64) {
    const int c = tid;
    const float* r = sraw + ((size_t)(b * 64 + c) * 4) * 6;
    float sI = 0.f, qI = 0.f, sX = 0.f, qX = 0.f, sY = 0.f, qY = 0.f;
    #pragma unroll
    for (int q = 0; q < 4; ++q) {
      sI += r[q * 6 + 0]; qI += r[q * 6 + 1];
      sX += r[q * 6 + 2]; qX += r[q * 6 + 3];
      sY += r[q * 6 + 4]; qY += r[q * 6 + 5];
    }
    const float n = 1.f / 16384.f;
    float m;
    m = sI * n; stl[c * 2] = m;           stl[c * 2 + 1] = rsqrtf(qI * n - m * m + EPS_);
    const int cx = 64 + 2 * c, cy = cx + 1;
    m = sX * n; stl[cx * 2] = m;          stl[cx * 2 + 1] = rsqrtf(qX * n - m * m + EPS_);
    m = sY * n; stl[cy * 2] = m;          stl[cy * 2 + 1] = rsqrtf(qY * n - m * m + EPS_);
  }
  __syncthreads();

  const float* hyp = wsm + OFF_HYP + (size_t)b * HYP_;
  unsigned short* wfin = (unsigned short*)(wsm + OFF_WFIN) + (size_t)b * 24576;
  unsigned short* wfsh = (unsigned short*)(wsm + OFF_WFSH) + (size_t)b * 24576;
  unsigned short* wfmid = (unsigned short*)(wsm + OFF_WFMID) + (size_t)b * 8192;
  unsigned short* wfout = (unsigned short*)(wsm + OFF_WFOUT) + (size_t)b * 8192;
  float* abIn = wsm + OFF_ABIN + b * 64;
  float* abSh = wsm + OFF_ABSH + b * 64;

  if (sl < 6) {
    const int base = sl * 2048;
    for (int i = tid; i < 2048; i += 256) {
      int idx = base + i;
      int j = idx & 7, ch = (idx >> 3) & 63, g2 = (idx >> 9) & 3, ks = idx >> 11;
      int k = ks * 32 + g2 * 8 + j;
      int fb = ((ks * 4 + g2) * 64 + ch) * 16;
      float inv = stl[k * 2 + 1];
      unsigned short h, l;
      split2(hyp[OFFI_WIN + ch * C3_ + k] * inv, h, l);
      wfin[fb + j] = h; wfin[fb + 8 + j] = l;
      split2(hyp[OFFI_WSH + ch * C3_ + k] * inv, h, l);
      wfsh[fb + j] = h; wfsh[fb + 8 + j] = l;
    }
  } else if (sl == 6) {
    for (int idx = tid; idx < 4096; idx += 256) {
      int j = idx & 7, ch = (idx >> 3) & 63, g2 = (idx >> 9) & 3, ks = idx >> 11;
      int k = ks * 32 + g2 * 8 + j;
      int fb = ((ks * 4 + g2) * 64 + ch) * 16;
      unsigned short h, l;
      split2(hyp[OFFI_WMID + ch * 64 + k], h, l);
      wfmid[fb + j] = h; wfmid[fb + 8 + j] = l;
      split2(hyp[OFFI_WOUT + ch * 64 + k], h, l);
      wfout[fb + j] = h; wfout[fb + 8 + j] = l;
    }
  } else {
    if (tid < 64) {
      int o = tid;
      float s1 = 0.f, s2 = 0.f;
      for (int cc = 0; cc < C3_; ++cc) {
        float m = stl[cc * 2] * stl[cc * 2 + 1];
        s1 = __builtin_fmaf(hyp[OFFI_WIN + o * C3_ + cc], m, s1);
        s2 = __builtin_fmaf(hyp[OFFI_WSH + o * C3_ + cc], m, s2);
      }
      abIn[o] = hyp[OFFI_BIN + o] - s1;
      abSh[o] = hyp[OFFI_BSH + o] - s2;
    }
  }
}

// ---------------- MFMA dynamic MLP, split-bf16 ------------------------------------
// block = (b, 64-px tile); 4 waves x 16 px. Identity channels read from fp32 out
// and split in-kernel; gx/gy unpacked from sob. Every GEMM = 3 MFMAs (hi/lo).
__global__ __launch_bounds__(256, 2) void mlp_mfma_kernel(
    float* __restrict__ outb, const unsigned int* __restrict__ sobu,
    const float* __restrict__ wsf, const float* __restrict__ leak) {
  __shared__ unsigned short yhi[64 * 200];
  __shared__ unsigned short ylo[64 * 200];
  __shared__ unsigned short hhi[64 * 72];
  __shared__ unsigned short hlo[64 * 72];
  const int bi = blockIdx.x;
  const int b = bi >> 8, t = bi & 255;
  const int px0 = t * 64;
  const int tid = threadIdx.x;

  // stage y tile (192 k x 64 px), swizzle: elem(px,k) at px*200 + (k ^ ((px>>3)<<3))
  const float* ob = outb + (size_t)b * F_ * NPIX_;
  const unsigned int* sbp = sobu + (size_t)b * 128 * NPIX_;
  #pragma unroll
  for (int it = 0; it < 12; ++it) {
    int ci = it * 256 + tid;
    int k = ci >> 4, pq = ci & 15;       // pixel-quad: px = pq*4 + r, px>>3 = pq>>1
    int kk = k ^ ((pq >> 1) << 3);
    unsigned short* ph = &yhi[(pq * 4) * 200 + kk];
    unsigned short* pl = &ylo[(pq * 4) * 200 + kk];
    if (k < 64) {
      float4 f = *(const float4*)(ob + (size_t)k * NPIX_ + px0 + pq * 4);
      unsigned short h, l;
      split2(f.x, h, l); ph[0 * 200] = h; pl[0 * 200] = l;
      split2(f.y, h, l); ph[1 * 200] = h; pl[1 * 200] = l;
      split2(f.z, h, l); ph[2 * 200] = h; pl[2 * 200] = l;
      split2(f.w, h, l); ph[3 * 200] = h; pl[3 * 200] = l;
    } else {
      uint4 v = *(const uint4*)(sbp + (size_t)(k - 64) * NPIX_ + px0 + pq * 4);
      ph[0 * 200] = (unsigned short)(v.x >> 16); pl[0 * 200] = (unsigned short)(v.x & 0xffff);
      ph[1 * 200] = (unsigned short)(v.y >> 16); pl[1 * 200] = (unsigned short)(v.y & 0xffff);
      ph[2 * 200] = (unsigned short)(v.z >> 16); pl[2 * 200] = (unsigned short)(v.z & 0xffff);
      ph[3 * 200] = (unsigned short)(v.w >> 16); pl[3 * 200] = (unsigned short)(v.w & 0xffff);
    }
  }
  __syncthreads();

  const int wave = tid >> 6, lane = tid & 63;
  const int lrow = lane & 15, g = lane >> 4;
  const int pxl = wave * 16 + lrow;  // this lane's A row (local px)
  const int sw = (pxl >> 3) << 3;
  const float lf = fminf(fmaxf(leak[0], 0.001f), 1000.f);
  const float* abIn = wsf + OFF_ABIN + b * 64;
  const float* abSh = wsf + OFF_ABSH + b * 64;
  const float* hyp = wsf + OFF_HYP + (size_t)b * HYP_;
  const unsigned short* wfin = (const unsigned short*)(wsf + OFF_WFIN) + (size_t)b * 24576;
  const unsigned short* wfsh = (const unsigned short*)(wsf + OFF_WFSH) + (size_t)b * 24576;
  const unsigned short* wfmid = (const unsigned short*)(wsf + OFF_WFMID) + (size_t)b * 8192;
  const unsigned short* wfout = (const unsigned short*)(wsf + OFF_WFOUT) + (size_t)b * 8192;

  // ---- h1 (64x192) + shortcut (64x192), shared A-frags ----
  f32x4 aH[4], aS[4];
  #pragma unroll
  for (int cg = 0; cg < 4; ++cg) {
    float b1 = abIn[cg * 16 + lrow], b2 = abSh[cg * 16 + lrow];
    aH[cg] = (f32x4){b1, b1, b1, b1};
    aS[cg] = (f32x4){b2, b2, b2, b2};
  }
  #pragma unroll
  for (int ks = 0; ks < 6; ++ks) {
    const int kb = pxl * 200 + ((ks * 32 + g * 8) ^ sw);
    bf16x8 ahi = *(const bf16x8*)&yhi[kb];
    bf16x8 alo = *(const bf16x8*)&ylo[kb];
    #pragma unroll
    for (int cg = 0; cg < 4; ++cg) {
      const unsigned short* p1 = wfin + (size_t)((ks * 4 + g) * 64 + cg * 16 + lrow) * 16;
      bf16x8 whi = *(const bf16x8*)p1;
      bf16x8 wlo = *(const bf16x8*)(p1 + 8);
      MM3(aH[cg], ahi, alo, whi, wlo);
      const unsigned short* p2 = wfsh + (size_t)((ks * 4 + g) * 64 + cg * 16 + lrow) * 16;
      whi = *(const bf16x8*)p2;
      wlo = *(const bf16x8*)(p2 + 8);
      MM3(aS[cg], ahi, alo, whi, wlo);
    }
  }
  // lrelu(h1) -> htile split planes [px][72]; D row=(lane>>4)*4+j -> px, col -> ch
  #pragma unroll
  for (int cg = 0; cg < 4; ++cg) {
    #pragma unroll
    for (int j = 0; j < 4; ++j) {
      float v = aH[cg][j];
      v = (v >= 0.f) ? v : NEG_ * v;
      unsigned short h, l;
      split2(v, h, l);
      const int o = (wave * 16 + g * 4 + j) * 72 + cg * 16 + lrow;
      hhi[o] = h; hlo[o] = l;
    }
  }
  __syncthreads();
  // ---- h2 (64x64) ----
  f32x4 aM[4];
  #pragma unroll
  for (int cg = 0; cg < 4; ++cg) {
    float bm = hyp[OFFI_BMID + cg * 16 + lrow];
    aM[cg] = (f32x4){bm, bm, bm, bm};
  }
  #pragma unroll
  for (int ks = 0; ks < 2; ++ks) {
    const int kb = pxl * 72 + ks * 32 + g * 8;
    bf16x8 ahi = *(const bf16x8*)&hhi[kb];
    bf16x8 alo = *(const bf16x8*)&hlo[kb];
    #pragma unroll
    for (int cg = 0; cg < 4; ++cg) {
      const unsigned short* p1 = wfmid + (size_t)((ks * 4 + g) * 64 + cg * 16 + lrow) * 16;
      bf16x8 whi = *(const bf16x8*)p1;
      bf16x8 wlo = *(const bf16x8*)(p1 + 8);
      MM3(aM[cg], ahi, alo, whi, wlo);
    }
  }
  __syncthreads();
  #pragma unroll
  for (int cg = 0; cg < 4; ++cg) {
    #pragma unroll
    for (int j = 0; j < 4; ++j) {
      float v = aM[cg][j];
      v = (v >= 0.f) ? v : NEG_ * v;
      unsigned short h, l;
      split2(v, h, l);
      const int o = (wave * 16 + g * 4 + j) * 72 + cg * 16 + lrow;
      hhi[o] = h; hlo[o] = l;
    }
  }
  __syncthreads();
  // ---- h3 (64x64) ----
  f32x4 aO[4];
  #pragma unroll
  for (int cg = 0; cg < 4; ++cg) {
    float bo = hyp[OFFI_BOUT + cg * 16 + lrow];
    aO[cg] = (f32x4){bo, bo, bo, bo};
  }
  #pragma unroll
  for (int ks = 0; ks < 2; ++ks) {
    const int kb = pxl * 72 + ks * 32 + g * 8;
    bf16x8 ahi = *(const bf16x8*)&hhi[kb];
    bf16x8 alo = *(const bf16x8*)&hlo[kb];
    #pragma unroll
    for (int cg = 0; cg < 4; ++cg) {
      const unsigned short* p1 = wfout + (size_t)((ks * 4 + g) * 64 + cg * 16 + lrow) * 16;
      bf16x8 whi = *(const bf16x8*)p1;
      bf16x8 wlo = *(const bf16x8*)(p1 + 8);
      MM3(aO[cg], ahi, alo, whi, wlo);
    }
  }
  // ---- out += lf * (h3 + shortcut) ----
  #pragma unroll
  for (int cg = 0; cg < 4; ++cg) {
    float* op = outb + ((size_t)(b * F_ + cg * 16 + lrow)) * NPIX_ + px0 + wave * 16 + g * 4;
    f32x4 cur = *(f32x4*)op;
    #pragma unroll
    for (int j = 0; j < 4; ++j) cur[j] += lf * (aO[cg][j] + aS[cg][j]);
    *(f32x4*)op = cur;
  }
}

// ---------------- epilogue: 3x3 convs ---------------------------------------------
__global__ __launch_bounds__(256, 4) void conv1_kernel(
    const float* __restrict__ in, const float* __restrict__ wT,
    const float* __restrict__ bias, float* __restrict__ outp) {
  const int bi = blockIdx.x;
  const int og = bi & 3, pxb = (bi >> 2) & 63, b = bi >> 8;
  const int p = pxb * 256 + threadIdx.x;
  const int row = p >> 7, col = p & 127;
  float acc[16];
  #pragma unroll
  for (int o = 0; o < 16; ++o) acc[o] = bias[og * 16 + o];
  const float* ip = in + (size_t)b * F_ * NPIX_;
  for (int c = 0; c < 64; ++c) {
    const float* pl = ip + (size_t)c * NPIX_;
    #pragma unroll
    for (int t = 0; t < 9; ++t) {
      const int dy = t / 3 - 1, dx = t % 3 - 1;
      const int r2 = row + dy, c2 = col + dx;
      float v = (r2 >= 0 && r2 < 128 && c2 >= 0 && c2 < 128) ? pl[r2 * HH_ + c2] : 0.f;
      const float* wp = wT + (c * 9 + t) * 64 + og * 16;
      #pragma unroll
      for (int o = 0; o < 16; ++o) acc[o] = __builtin_fmaf(v, wp[o], acc[o]);
    }
  }
  float* opz = outp + (size_t)(b * F_ + og * 16) * NPIX_ + p;
  #pragma unroll
  for (int o = 0; o < 16; ++o) {
    float v = acc[o];
    opz[(size_t)o * NPIX_] = (v >= 0.f) ? v : NEG_ * v;
  }
}

__global__ __launch_bounds__(256, 4) void conv2_kernel(
    const float* __restrict__ h, const float* __restrict__ wT,
    const float* __restrict__ bias, float* __restrict__ outb) {
  const int bi = blockIdx.x;
  const int og = bi & 3, pxb = (bi >> 2) & 63, b = bi >> 8;
  const int p = pxb * 256 + threadIdx.x;
  const int row = p >> 7, col = p & 127;
  float acc[16];
  #pragma unroll
  for (int o = 0; o < 16; ++o) acc[o] = bias[og * 16 + o];
  const float* ip = h + (size_t)b * F_ * NPIX_;
  for (int c = 0; c < 64; ++c) {
    const float* pl = ip + (size_t)c * NPIX_;
    #pragma unroll
    for (int t = 0; t < 9; ++t) {
      const int dy = t / 3 - 1, dx = t % 3 - 1;
      const int r2 = row + dy, c2 = col + dx;
      float v = (r2 >= 0 && r2 < 128 && c2 >= 0 && c2 < 128) ? pl[r2 * HH_ + c2] : 0.f;
      const float* wp = wT + (c * 9 + t) * 64 + og * 16;
      #pragma unroll
      for (int o = 0; o < 16; ++o) acc[o] = __builtin_fmaf(v, wp[o], acc[o]);
    }
  }
  float* opz = outb + (size_t)(b * F_ + og * 16) * NPIX_ + p;
  #pragma unroll
  for (int o = 0; o < 16; ++o) opz[(size_t)o * NPIX_] = opz[(size_t)o * NPIX_] + acc[o];
}

__global__ __launch_bounds__(256, 4) void convimg_kernel(
    const float* __restrict__ outb, const float* __restrict__ wT,
    const float* __restrict__ bias, float* __restrict__ img) {
  __shared__ float part[2 * 128 * 3];
  const int bi = blockIdx.x;
  const int b = bi >> 7, pxb = bi & 127;
  const int tid = threadIdx.x;
  const int px = tid & 127;
  const int hf = __builtin_amdgcn_readfirstlane(tid >> 7);
  const int p = pxb * 128 + px;
  const int row = p >> 7, col = p & 127;
  float a0 = 0.f, a1 = 0.f, a2 = 0.f;
  const float* ip = outb + (size_t)b * F_ * NPIX_;
  for (int cc = 0; cc < 32; ++cc) {
    const int c = hf * 32 + cc;
    const float* pl = ip + (size_t)c * NPIX_;
    #pragma unroll
    for (int t = 0; t < 9; ++t) {
      const int dy = t / 3 - 1, dx = t % 3 - 1;
      const int r2 = row + dy, c2 = col + dx;
      float v = (r2 >= 0 && r2 < 128 && c2 >= 0 && c2 < 128) ? pl[r2 * HH_ + c2] : 0.f;
      const float* wp = wT + (c * 9 + t) * 3;
      a0 = __builtin_fmaf(v, wp[0], a0);
      a1 = __builtin_fmaf(v, wp[1], a1);
      a2 = __builtin_fmaf(v, wp[2], a2);
    }
  }
  part[(hf * 128 + px) * 3 + 0] = a0;
  part[(hf * 128 + px) * 3 + 1] = a1;
  part[(hf * 128 + px) * 3 + 2] = a2;
  __syncthreads();
  if (hf == 0) {
    float r0 = a0 + part[(128 + px) * 3 + 0] + bias[0];
    float r1 = a1 + part[(128 + px) * 3 + 1] + bias[1];
    float r2 = a2 + part[(128 + px) * 3 + 2] + bias[2];
    img[((size_t)b * 3 + 0) * NPIX_ + p] = fminf(fmaxf(r0, -1.f), 1.f);
    img[((size_t)b * 3 + 1) * NPIX_ + p] = fminf(fmaxf(r1, -1.f), 1.f);
    img[((size_t)b * 3 + 2) * NPIX_ + p] = fminf(fmaxf(r2, -1.f), 1.f);
  }
}

extern "C" void kernel_launch(void* const* d_in, const int* in_sizes, int n_in,
                              void* d_out, int out_size, void* d_ws, size_t ws_size,
                              hipStream_t stream) {
  const float* lat = (const float*)d_in[0];
  const float* ca_init = (const float*)d_in[1];
  const float* leak = (const float*)d_in[2];
  const float* hyper_w = (const float*)d_in[3];
  const float* hyper_b = (const float*)d_in[4];
  const float* res_w1 = (const float*)d_in[5];
  const float* res_b1 = (const float*)d_in[6];
  const float* res_w2 = (const float*)d_in[7];
  const float* res_b2 = (const float*)d_in[8];
  const float* img_w = (const float*)d_in[9];
  const float* img_b = (const float*)d_in[10];
  float* out = (float*)d_out;
  float* ws = (float*)d_ws;
  unsigned int* sobu = (unsigned int*)(ws + OFF_SOB);

  hyper_gemm_kernel<<<(HYP_ + 3) / 4, 256, 0, stream>>>(lat, hyper_w, hyper_b, ws + OFF_HYP);
  hipMemcpyAsync(ws + OFF_OUT, ca_init, (size_t)B_ * F_ * NPIX_ * sizeof(float),
                 hipMemcpyDeviceToDevice, stream);

  for (int st = 0; st < 16; ++st) {
    sobel_stats_kernel<<<1024, 256, 0, stream>>>(ws + OFF_OUT, sobu, ws + OFF_SRAW);
    wadjust_kernel<<<32, 256, 0, stream>>>(ws);
    mlp_mfma_kernel<<<1024, 256, 0, stream>>>(ws + OFF_OUT, sobu, ws, leak);
  }

  prep_convw_kernel<<<144, 256, 0, stream>>>(res_w1, res_w2, img_w,
                                             ws + OFF_CW1, ws + OFF_CW2, ws + OFF_CWIMG);
  conv1_kernel<<<1024, 256, 0, stream>>>(ws + OFF_OUT, ws + OFF_CW1, res_b1,
                                         (float*)(ws + OFF_TMP));
  conv2_kernel<<<1024, 256, 0, stream>>>((float*)(ws + OFF_TMP), ws + OFF_CW2, res_b2,
                                         ws + OFF_OUT);
  convimg_kernel<<<512, 256, 0, stream>>>(ws + OFF_OUT, ws + OFF_CWIMG, img_b, out);
}